// Round 1
// 380.583 us; speedup vs baseline: 1.0030x; 1.0030x over previous
//
#include <hip/hip_runtime.h>
#include <hip/hip_bf16.h>

typedef unsigned short u16;
typedef __bf16 bf16x8 __attribute__((ext_vector_type(8)));
typedef float f32x4 __attribute__((ext_vector_type(4)));

// B=256, M=512, D=512, C=8, units 512/256/128, TEMP=0.5 (1/T = 2)
// Inputs: bf16. Output: FLOAT32: [z (8*256*128) | losses (8)].

__device__ __forceinline__ float bf2f(u16 u) {
    union { float f; unsigned int i; } x; x.i = ((unsigned int)u) << 16; return x.f;
}
__device__ __forceinline__ u16 f2bf(float f) {
    union { float f; unsigned int i; } x; x.f = f;
    unsigned int r = x.i + 0x7FFFu + ((x.i >> 16) & 1u);
    return (u16)(r >> 16);
}

// ---------------------------------------------------------------------------
// Masked sum-pool, 1024 threads (16 waves) per block, one block per b.
// ---------------------------------------------------------------------------
__global__ __launch_bounds__(1024) void pool_kernel(
    const u16* __restrict__ ec, const u16* __restrict__ mask,
    u16* __restrict__ pooled)
{
    int b = blockIdx.x, tid = threadIdx.x;
    __shared__ float wm[512];
    __shared__ float red[16][512];   // 32 KB
    if (tid < 512)
        wm[tid] = (bf2f(mask[b * 512 + tid]) == 0.0f) ? 1.0f : 0.0f;  // keep when mask==0
    __syncthreads();
    int g = tid & 63, mo = tid >> 6;   // wave mo handles m % 16 == mo (wave-uniform branch)
    float acc[8];
    #pragma unroll
    for (int j = 0; j < 8; j++) acc[j] = 0.0f;
    const u16* base = ec + (size_t)b * 512 * 512;
    for (int m = mo; m < 512; m += 16) {
        if (wm[m] != 0.0f) {
            union { uint4 v; u16 s[8]; } u;
            u.v = *(const uint4*)&base[(size_t)m * 512 + g * 8];
            #pragma unroll
            for (int j = 0; j < 8; j++) acc[j] += bf2f(u.s[j]);
        }
    }
    #pragma unroll
    for (int j = 0; j < 8; j++) red[mo][g * 8 + j] = acc[j];
    __syncthreads();
    if (tid < 512) {
        float s = 0.0f;
        #pragma unroll
        for (int k = 0; k < 16; k++) s += red[k][tid];
        pooled[(size_t)b * 512 + tid] = f2bf(s);
    }
}

// ---------------------------------------------------------------------------
// 64x64-tile bf16 GEMM + bias + relu -> bf16. 512 threads / 8 waves
// (wave tile 16x32, 2 waves/SIMD for latency hiding), W transposed during LDS
// stage, double-buffered LDS + register prefetch (one barrier per K-iter).
// A: [256 x K] rm (per-class stride aBatch), W: [c][K][N] rm, out: [c][256][N].
// ---------------------------------------------------------------------------
__global__ __launch_bounds__(512) void mlp_gemm64(
    const u16* __restrict__ A, const u16* __restrict__ W,
    const u16* __restrict__ bias, u16* __restrict__ out,
    int K, int N, int aBatch, int mtiles, int ntiles)
{
    int bid = blockIdx.x;
    int per_c = mtiles * ntiles;
    int c = bid / per_c, rem = bid % per_c;
    int mt = rem / ntiles, nt = rem % ntiles;
    const u16* aBase = A + (size_t)c * aBatch + (size_t)mt * 64 * K;
    const u16* wBase = W + (size_t)c * K * N + nt * 64;
    __shared__ __align__(16) u16 As[2][64][72];
    __shared__ __align__(16) u16 Bs[2][64][72];   // [n][k]
    int tid = threadIdx.x;
    int w = tid >> 6, l15 = tid & 15, q = (tid >> 4) & 3;
    int wm = w >> 1, wn = w & 1;                 // wave tile: rows wm*16, cols wn*32
    int r0 = tid >> 3, kc0 = tid & 7;            // staging coords: 1 uint4 each of A and W
    f32x4 acc[2];
    #pragma unroll
    for (int t = 0; t < 2; t++)
        #pragma unroll
        for (int e = 0; e < 4; e++) acc[t][e] = 0.0f;

    uint4 aReg, wReg;
    // prologue: load k0 = 0
    aReg = *(const uint4*)&aBase[(size_t)r0 * K + kc0 * 8];
    wReg = *(const uint4*)&wBase[(size_t)r0 * N + kc0 * 8];

    int nIter = K >> 6;
    for (int it = 0; it < nIter; ++it) {
        int cur = it & 1;
        // commit staged regs to LDS buffer `cur` (B transposed: scatter u16)
        *(uint4*)&As[cur][r0][kc0 * 8] = aReg;
        {
            union { uint4 v; u16 s[8]; } u; u.v = wReg;
            #pragma unroll
            for (int j = 0; j < 8; j++) Bs[cur][kc0 * 8 + j][r0] = u.s[j];
        }
        // issue next-iter global loads (overlap with barrier + MFMA below)
        if (it + 1 < nIter) {
            int k0n = (it + 1) * 64;
            aReg = *(const uint4*)&aBase[(size_t)r0 * K + k0n + kc0 * 8];
            wReg = *(const uint4*)&wBase[(size_t)(k0n + r0) * N + kc0 * 8];
        }
        __syncthreads();
        #pragma unroll
        for (int ks = 0; ks < 64; ks += 32) {
            bf16x8 av = *(const bf16x8*)&As[cur][wm * 16 + l15][ks + q * 8];
            #pragma unroll
            for (int t = 0; t < 2; t++) {
                bf16x8 bv = *(const bf16x8*)&Bs[cur][wn * 32 + t * 16 + l15][ks + q * 8];
                acc[t] = __builtin_amdgcn_mfma_f32_16x16x32_bf16(av, bv, acc[t], 0, 0, 0);
            }
        }
        // no end barrier: next iter writes the OTHER buffer; the single barrier
        // above separates those writes from this buffer's prior readers.
    }
    #pragma unroll
    for (int t = 0; t < 2; t++) {
        int col = nt * 64 + wn * 32 + t * 16 + l15;
        float bv = bf2f(bias[c * N + col]);
        #pragma unroll
        for (int r = 0; r < 4; r++) {
            int row = mt * 64 + wm * 16 + q * 4 + r;
            float v = acc[t][r] + bv;
            v = v > 0.0f ? v : 0.0f;
            out[((size_t)c * 256 + row) * N + col] = f2bf(v);
        }
    }
}

// ---------------------------------------------------------------------------
// Layer 3 (K=256, N=128) + fused L2 normalize. 128 blocks: (c, 16-row tile).
// 4 waves; wave w covers cols w*32..w*32+31, all 16 rows. Cross-wave ssq via LDS.
// ---------------------------------------------------------------------------
__global__ __launch_bounds__(256) void mlp_gemm3_norm(
    const u16* __restrict__ A, const u16* __restrict__ W,
    const u16* __restrict__ bias, float* __restrict__ zout, u16* __restrict__ zbf)
{
    const int K = 256, N = 128;
    int bid = blockIdx.x;
    int c = bid >> 4, mt = bid & 15;
    const u16* aBase = A + ((size_t)c * 256 + mt * 16) * K;
    const u16* wBase = W + (size_t)c * K * N;
    __shared__ __align__(16) u16 As[16][72];
    __shared__ __align__(16) u16 Bs[128][72];   // [n][k]
    __shared__ float ssq_s[4][16];
    __shared__ float scale_s[16];
    int tid = threadIdx.x;
    int w = tid >> 6, l15 = tid & 15, q = (tid >> 4) & 3;
    f32x4 acc[2];
    #pragma unroll
    for (int t = 0; t < 2; t++)
        #pragma unroll
        for (int e = 0; e < 4; e++) acc[t][e] = 0.0f;

    for (int k0 = 0; k0 < K; k0 += 64) {
        if (tid < 128) {
            int r = tid >> 3, kc = tid & 7;
            *(uint4*)&As[r][kc * 8] = *(const uint4*)&aBase[(size_t)r * K + k0 + kc * 8];
        }
        #pragma unroll
        for (int i = 0; i < 4; i++) {
            int idx = tid + i * 256;
            int kk = idx >> 4, n8 = (idx & 15) * 8;
            union { uint4 v; u16 s[8]; } u;
            u.v = *(const uint4*)&wBase[(size_t)(k0 + kk) * N + n8];
            #pragma unroll
            for (int j = 0; j < 8; j++) Bs[n8 + j][kk] = u.s[j];
        }
        __syncthreads();
        #pragma unroll
        for (int ks = 0; ks < 64; ks += 32) {
            bf16x8 av = *(const bf16x8*)&As[l15][ks + q * 8];
            #pragma unroll
            for (int t = 0; t < 2; t++) {
                bf16x8 bv = *(const bf16x8*)&Bs[w * 32 + t * 16 + l15][ks + q * 8];
                acc[t] = __builtin_amdgcn_mfma_f32_16x16x32_bf16(av, bv, acc[t], 0, 0, 0);
            }
        }
        __syncthreads();
    }
    // epilogue: bias + relu, per-row sum of squares across the full 128 cols
    float val[2][4];
    float ssq[4] = {0.f, 0.f, 0.f, 0.f};
    #pragma unroll
    for (int t = 0; t < 2; t++) {
        float bv = bf2f(bias[c * N + w * 32 + t * 16 + l15]);
        #pragma unroll
        for (int r = 0; r < 4; r++) {
            float v = acc[t][r] + bv;
            v = v > 0.0f ? v : 0.0f;
            val[t][r] = v;
            ssq[r] += v * v;
        }
    }
    #pragma unroll
    for (int off = 1; off < 16; off <<= 1)
        #pragma unroll
        for (int r = 0; r < 4; r++) ssq[r] += __shfl_xor(ssq[r], off);
    if (l15 == 0) {
        #pragma unroll
        for (int r = 0; r < 4; r++) ssq_s[w][q * 4 + r] = ssq[r];
    }
    __syncthreads();
    if (tid < 16) {
        float s = ssq_s[0][tid] + ssq_s[1][tid] + ssq_s[2][tid] + ssq_s[3][tid];
        scale_s[tid] = rsqrtf(fmaxf(s, 1e-12f));
    }
    __syncthreads();
    #pragma unroll
    for (int t = 0; t < 2; t++)
        #pragma unroll
        for (int r = 0; r < 4; r++) {
            int row = mt * 16 + q * 4 + r;
            int col = w * 32 + t * 16 + l15;
            float zv = val[t][r] * scale_s[q * 4 + r];
            size_t o = ((size_t)c * 256 + row) * 128 + col;
            zout[o] = zv;
            zbf[o] = f2bf(zv);
        }
}

// ---------------------------------------------------------------------------
// Fused contrastive loss: one block per class (1024 threads / 16 waves).
// Full z_c (256x128 bf16 = 64 KB) staged in LDS; wave (rw,cw) computes the
// 64x64 tile of ip = (z z^T)/T with zeroed diag; per-row sum exp / masked
// sums reduced in-block; loss written directly. No workspace, no atomics.
// ---------------------------------------------------------------------------
__global__ __launch_bounds__(1024) void contrast_loss(
    const u16* __restrict__ z, const int* __restrict__ label,
    float* __restrict__ losses)
{
    int c = blockIdx.x;
    int tid = threadIdx.x;
    int w = tid >> 6, l15 = tid & 15, q = (tid >> 4) & 3;
    int rw = w >> 2, cw = w & 3;   // wave tile: rows rw*64, cols cw*64
    __shared__ __align__(16) u16 Zk[256][136];   // 69.6 KB, pad 136 (68 dw, +4 mod 32)
    __shared__ float lm1[256];
    __shared__ float npw[16];
    __shared__ float pr_s[4][256];
    __shared__ float p1_s[4][256];
    __shared__ float p0_s[4][256];
    __shared__ float term_s[256];
    __shared__ float red4[4];

    const u16* zc = z + (size_t)c * 256 * 128;
    #pragma unroll
    for (int i = 0; i < 4; i++) {
        int idx = tid + i * 1024;
        int r = idx >> 4, kc = idx & 15;
        *(uint4*)&Zk[r][kc * 8] = *(const uint4*)&zc[(size_t)r * 128 + kc * 8];
    }
    float m1 = 0.0f;
    if (tid < 256) {
        m1 = (label[tid * 8 + c] == 1) ? 1.0f : 0.0f;
        lm1[tid] = m1;
    }
    // num_p: per-wave reduce (only waves 0..3 carry nonzero)
    float nps = m1;
    #pragma unroll
    for (int off = 1; off < 64; off <<= 1) nps += __shfl_xor(nps, off);
    if ((tid & 63) == 0) npw[w] = nps;
    __syncthreads();

    f32x4 acc[4][4];   // [a (row frag)][t (col frag)] -> 64 f32
    #pragma unroll
    for (int a = 0; a < 4; a++)
        #pragma unroll
        for (int t = 0; t < 4; t++)
            #pragma unroll
            for (int e = 0; e < 4; e++) acc[a][t][e] = 0.0f;
    #pragma unroll
    for (int ks = 0; ks < 128; ks += 32) {
        bf16x8 av[4], bv[4];
        #pragma unroll
        for (int a = 0; a < 4; a++)
            av[a] = *(const bf16x8*)&Zk[rw * 64 + a * 16 + l15][ks + q * 8];
        #pragma unroll
        for (int t = 0; t < 4; t++)
            bv[t] = *(const bf16x8*)&Zk[cw * 64 + t * 16 + l15][ks + q * 8];
        #pragma unroll
        for (int a = 0; a < 4; a++)
            #pragma unroll
            for (int t = 0; t < 4; t++)
                acc[a][t] = __builtin_amdgcn_mfma_f32_16x16x32_bf16(av[a], bv[t], acc[a][t], 0, 0, 0);
    }
    // per-row partials: rows rbg = rw*64 + a*16 + q*4 + r, cols kbg = cw*64 + t*16 + l15
    #pragma unroll
    for (int a = 0; a < 4; a++) {
        float pr[4] = {0.f, 0.f, 0.f, 0.f};
        float p1[4] = {0.f, 0.f, 0.f, 0.f};
        float p0[4] = {0.f, 0.f, 0.f, 0.f};
        #pragma unroll
        for (int t = 0; t < 4; t++) {
            int kbg = cw * 64 + t * 16 + l15;
            float mm = lm1[kbg];
            #pragma unroll
            for (int r = 0; r < 4; r++) {
                int rbg = rw * 64 + a * 16 + q * 4 + r;
                float v = (rbg == kbg) ? 0.0f : acc[a][t][r] * 2.0f;  // /TEMP, zero diag
                pr[r] += __expf(v);
                p1[r] += v * mm;
                p0[r] += v * (1.0f - mm);
            }
        }
        #pragma unroll
        for (int off = 1; off < 16; off <<= 1)
            #pragma unroll
            for (int r = 0; r < 4; r++) {
                pr[r] += __shfl_xor(pr[r], off);
                p1[r] += __shfl_xor(p1[r], off);
                p0[r] += __shfl_xor(p0[r], off);
            }
        if (l15 == 0) {
            #pragma unroll
            for (int r = 0; r < 4; r++) {
                int rbg = rw * 64 + a * 16 + q * 4 + r;
                pr_s[cw][rbg] = pr[r];
                p1_s[cw][rbg] = p1[r];
                p0_s[cw][rbg] = p0[r];
            }
        }
    }
    __syncthreads();
    if (tid < 256) {
        float rt = pr_s[0][tid] + pr_s[1][tid] + pr_s[2][tid] + pr_s[3][tid];
        float s1 = p1_s[0][tid] + p1_s[1][tid] + p1_s[2][tid] + p1_s[3][tid];
        float s0 = p0_s[0][tid] + p0_s[1][tid] + p0_s[2][tid] + p0_s[3][tid];
        float np = 0.0f;
        #pragma unroll
        for (int k = 0; k < 16; k++) np += npw[k];
        float m = lm1[tid];
        float num_vec = (m > 0.0f) ? np : 256.0f - np;
        float numer = (m > 0.0f) ? s1 : s0;
        term_s[tid] = numer / num_vec - __logf(rt);
    }
    __syncthreads();
    // final reduce of 256 terms (waves 0..3)
    if (tid < 256) {
        float t4 = term_s[tid];
        #pragma unroll
        for (int off = 1; off < 64; off <<= 1) t4 += __shfl_xor(t4, off);
        if ((tid & 63) == 0) red4[w] = t4;
    }
    __syncthreads();
    if (tid == 0) losses[c] = -(red4[0] + red4[1] + red4[2] + red4[3]);
}

// ---------------------------------------------------------------------------
extern "C" void kernel_launch(void* const* d_in, const int* in_sizes, int n_in,
                              void* d_out, int out_size, void* d_ws, size_t ws_size,
                              hipStream_t stream) {
    (void)in_sizes; (void)n_in; (void)ws_size;
    const u16* ec   = (const u16*)d_in[0];
    const u16* mask = (const u16*)d_in[1];
    const int* label = (const int*)d_in[2];
    const u16* W1 = (const u16*)d_in[3];
    const u16* b1 = (const u16*)d_in[4];
    const u16* W2 = (const u16*)d_in[5];
    const u16* b2 = (const u16*)d_in[6];
    const u16* W3 = (const u16*)d_in[7];
    const u16* b3 = (const u16*)d_in[8];
    float* zout = (float*)d_out;                 // fp32 output: z then losses
    char* ws = (char*)d_ws;
    // workspace layout (bytes) — total ~3.9 MB
    u16* pooled = (u16*)(ws + 0);          // 256*512*2   =   262,144
    u16* h1     = (u16*)(ws + 262144);     // 8*256*512*2 = 2,097,152
    u16* h2     = (u16*)(ws + 2359296);    // 8*256*256*2 = 1,048,576
    u16* zbf    = (u16*)(ws + 3407872);    // 8*256*128*2 =   524,288

    pool_kernel<<<256, 1024, 0, stream>>>(ec, mask, pooled);
    mlp_gemm64<<<256, 512, 0, stream>>>(pooled, W1, b1, h1, 512, 512, 0, 4, 8);
    mlp_gemm64<<<128, 512, 0, stream>>>(h1, W2, b2, h2, 512, 256, 256 * 512, 4, 4);
    mlp_gemm3_norm<<<128, 256, 0, stream>>>(h2, W3, b3, zout, zbf);
    contrast_loss<<<8, 1024, 0, stream>>>(zbf, label, zout + (out_size - 8));
}